// Round 4
// baseline (25.578 us; speedup 1.0000x reference)
//
#include <hip/hip_runtime.h>
#include <stdint.h>

#define BATCH 512
#define NBINS 7
#define TOTAL 100000
#define FXSCALE 16777216.0f   // 2^24 fixed-point scale for deterministic atomic sum

// bin offsets / sizes (INPUT_BINS = 100,200,500,1000,5000,20000,73200)
__device__ __constant__ int c_off[NBINS] = {0, 100, 300, 800, 1800, 6800, 26800};
__device__ __constant__ int c_nb[NBINS]  = {100, 200, 500, 1000, 5000, 20000, 73200};

__device__ __forceinline__ uint64_t mix64(uint64_t z) {
    z += 0x9E3779B97F4A7C15ULL;
    z = (z ^ (z >> 30)) * 0xBF58476D1CE4E5B9ULL;
    z = (z ^ (z >> 27)) * 0x94D049BB133111EBULL;
    return z ^ (z >> 31);
}

// One block per batch row; 8 waves:
//   waves 0..3 : small bins — single-pass online logsumexp (float4)
//   waves 4..6 : large bins — 20 negatives via one ballot round (speculative gather)
//   wave  7    : idle
// Tail: thread 0 adds the row loss (int64 fixed-point) to a device accumulator;
// the 512th arriver converts and writes out[0..1]. Integer atomics => bit-
// deterministic result independent of block arrival order.
__global__ __launch_bounds__(512) void fused_row_kernel(const float* __restrict__ logits,
                                                        const int* __restrict__ targets,
                                                        const int* __restrict__ mask,
                                                        unsigned long long* __restrict__ acc,
                                                        unsigned int* __restrict__ ctr,
                                                        float* __restrict__ out) {
    int b = blockIdx.x;
    int tid = threadIdx.x;
    int wave = tid >> 6;
    int lane = tid & 63;

    __shared__ float terms[7];

    if (wave < 4) {
        // ---------- small bin: term = obs[t] ? (logsumexp(bin) - row[t]) : 0
        int off = c_off[wave], nb = c_nb[wave];
        const float* row = logits + (size_t)b * TOTAL + off;
        const float4* r4 = (const float4*)row;   // off, nb multiples of 4
        int n4 = nb >> 2;

        float m_l = -INFINITY, s_l = 0.f;
        for (int j = lane; j < n4; j += 64) {
            float4 v = r4[j];
            float mv = fmaxf(fmaxf(v.x, v.y), fmaxf(v.z, v.w));
            float mn = fmaxf(m_l, mv);
            s_l = s_l * expf(m_l - mn)
                + expf(v.x - mn) + expf(v.y - mn) + expf(v.z - mn) + expf(v.w - mn);
            m_l = mn;
        }
        float m = m_l;
        for (int k = 32; k; k >>= 1) m = fmaxf(m, __shfl_xor(m, k));
        float c = s_l * expf(m_l - m);           // 0 for empty lanes
        for (int k = 32; k; k >>= 1) c += __shfl_xor(c, k);

        if (lane == 0) {
            float lse = m + logf(c);
            int t = targets[b * NBINS + wave];
            bool obs_t = (mask[(size_t)b * TOTAL + off + t] == 0);   // obs = ~mask
            terms[wave] = obs_t ? (lse - row[t]) : 0.f;
        }
    } else if (wave < 7) {
        // ---------- large bin: lse(target + 20 sampled negatives) - target
        int bin = wave;
        int off = c_off[bin], nb = c_nb[bin];
        const float* row = logits + (size_t)b * TOTAL + off;
        const int* mrow = mask + (size_t)b * TOTAL + off;

        int t = targets[b * NBINS + bin];
        float tv = row[t];

        int task = b * 3 + (bin - 4);
        float m_l = -INFINITY, s_l = 0.f;
        int have = 0;
        for (int r = 0; r < 4 && have < 20; ++r) {   // wave-uniform; round 0 covers ~all
            uint64_t h = mix64(((uint64_t)task << 20) | ((uint64_t)r << 6) | (uint64_t)lane);
            int pos = (int)(((h >> 32) * (uint64_t)nb) >> 32);   // uniform [0,nb)
            int mk = mrow[pos];
            float v = row[pos];                  // speculative gather, same round-trip
            bool obs = (mk == 0);
            unsigned long long bal = __ballot(obs);
            int cnt = __popcll(bal);
            int take = min(cnt, 20 - have);
            int j = __popcll(bal & ((1ULL << lane) - 1ULL));     // rank among observed
            if (obs && j < take) {
                float mn = fmaxf(m_l, v);
                s_l = s_l * expf(m_l - mn) + expf(v - mn);
                m_l = mn;
            }
            have += take;
        }
        float m = fmaxf(m_l, tv);
        for (int k = 32; k; k >>= 1) m = fmaxf(m, __shfl_xor(m, k));
        float c = s_l * expf(m_l - m);
        for (int k = 32; k; k >>= 1) c += __shfl_xor(c, k);

        if (lane == 0) terms[bin] = m + logf(c + expf(tv - m)) - tv;
    }

    __syncthreads();
    if (tid == 0) {
        float rl = terms[0] + terms[1] + terms[2] + terms[3]
                 + terms[4] + terms[5] + terms[6];
        // all terms are -log_softmax values => >= 0; fixed-point is exact-order-free
        unsigned long long s = (unsigned long long)llrintf(rl * FXSCALE);
        atomicAdd(acc, s);
        __threadfence();                          // release our contribution
        unsigned int old = atomicAdd(ctr, 1u);
        if (old == BATCH - 1) {                   // 512th arriver: everyone's add visible
            __threadfence();                      // acquire
            unsigned long long tot = atomicAdd(acc, 0ULL);  // coherent read
            float loss = (float)((double)tot / (double)FXSCALE);
            out[0] = loss;
            out[1] = loss / (512.0f * 0.69314718055994530942f);  // loss / (B*ln2)
        }
    }
}

extern "C" void kernel_launch(void* const* d_in, const int* in_sizes, int n_in,
                              void* d_out, int out_size, void* d_ws, size_t ws_size,
                              hipStream_t stream) {
    const int*   targets = (const int*)d_in[0];
    const float* logits  = (const float*)d_in[1];
    const int*   mask    = (const int*)d_in[2];
    // d_in[3..5] = input_bins / nb_negative / n_samples — hardcoded above.

    unsigned long long* acc = (unsigned long long*)d_ws;        // 8 B
    unsigned int*       ctr = (unsigned int*)((char*)d_ws + 8); // 4 B
    float* out = (float*)d_out;

    // zero accumulator + arrival counter each call (graph-legal memset node)
    hipMemsetAsync(d_ws, 0, 16, stream);

    fused_row_kernel<<<BATCH, 512, 0, stream>>>(logits, targets, mask, acc, ctr, out);
}